// Round 7
// baseline (121.675 us; speedup 1.0000x reference)
//
#include <hip/hip_runtime.h>
#include <stdint.h>

typedef __attribute__((ext_vector_type(8))) short bf16x8;
typedef __attribute__((ext_vector_type(4))) float f32x4;

#define MFMA16(a, b, c) __builtin_amdgcn_mfma_f32_16x16x32_bf16((a), (b), (c), 0, 0, 0)

static __device__ __forceinline__ unsigned short f2bf(float f) {
  union { float f; unsigned int u; } cv;
  cv.f = f;
  return (unsigned short)((cv.u + 0x7fffu + ((cv.u >> 16) & 1u)) >> 16);
}

#define BATCH 8192
#define ROWD  2128
#define HID   512
#define LATD  256
#define KC1   272            // 8-elem k-chunks for layer 1 (272*8 = 2176, zero-padded)
#define NT1   68             // 32-k tiles (68*32 = 2176; trailing tiles zero-padded)
#define HSL_TW (BATCH * HID) // ushorts per tower in h_sl

// ---------- prep: k-chunked transpose-cast ----------
__global__ __launch_bounds__(256) void ASAECF_tcast(
    const float* __restrict__ in0, const float* __restrict__ in1,
    unsigned short* __restrict__ out, int N, int lgN, int Kin, int KC, int perm)
{
  const float* __restrict__ in = blockIdx.z ? in1 : in0;
  unsigned short* __restrict__ o = out + (size_t)blockIdx.z * KC * N * 8;
  const int s = blockIdx.x * 256 + threadIdx.x;   // slot index
  const int kc = s >> lgN, n = s & (N - 1);
  unsigned short v[8];
#pragma unroll
  for (int e = 0; e < 8; ++e) {
    const int k = kc * 8 + e;
    float f = 0.0f;
    if (k < Kin) {
      const int src = perm ? (k < 128 ? k + 2000 : k - 128) : k;
      f = in[(size_t)src * N + n];
    }
    v[e] = f2bf(f);
  }
  *(uint4*)(o + (size_t)s * 8) = *(const uint4*)v;
}

// ---------- GEMM1: h = relu(gather(look) @ W1p + b1) ----------
// BM=128 (halves the dominant B re-read traffic: 570 -> 285 MB), BN=512, BK=32.
// 1024 threads = 16 waves (2 M x 8 N), wave tile 64x64, 4 waves/SIMD TLP.
// B fragments read directly from L2-resident w1s (no reg-prefetch; TLP hides).
// A: random-row gather pipelined 2 tiles ahead in regs, LDS double-buffered.
__global__ __launch_bounds__(1024) void ASAECF_gemm1(
    const int* __restrict__ x,
    const float* __restrict__ ulook, const float* __restrict__ ilook,
    const unsigned short* __restrict__ w1s,   // [2][KC1][512][8]
    const float* __restrict__ ub1, const float* __restrict__ ib1,
    unsigned short* __restrict__ hsl)         // [2][chunk64][kc][row64][8]
{
  // tower<->XCD partition: XCDs 0-3 -> tower 0, XCDs 4-7 -> tower 1
  const int bid   = blockIdx.x;             // 0..127
  const int xcd   = bid & 7;
  const int tower = xcd >> 2;
  const int mb    = (bid >> 3) * 4 + (xcd & 3);   // 0..63

  const float* __restrict__ look = tower ? ilook : ulook;
  const unsigned short* __restrict__ w1 = w1s + (size_t)tower * KC1 * HID * 8;
  const float* __restrict__ b1 = tower ? ib1 : ub1;
  unsigned short* __restrict__ hout = hsl + (size_t)tower * HSL_TW;

  __shared__ unsigned short Ab[2][128 * 40];  // 128 rows x 32 k, 80-B padded rows

  const int tid  = threadIdx.x;
  const int lane = tid & 63, wid = tid >> 6;
  const int wm   = wid >> 3, wn = wid & 7;    // wave tile: rows wm*64, cols wn*64
  const int fr   = lane & 15, fq = lane >> 4;
  const int row0 = mb * 128;

  // A staging: thread -> (row ar, 4 consecutive k at ak)
  const int ar = tid >> 3, ak = (tid & 7) * 4;
  const long long arow = (long long)x[(row0 + ar) * 2 + tower] * ROWD + ak;

  // B fragment offsets within one k-tile slab (4*512*8 ushorts)
  int boff[4];
#pragma unroll
  for (int n = 0; n < 4; ++n)
    boff[n] = (fq * 512 + wn * 64 + n * 16 + fr) * 8;

  auto loadA = [&](int tt) -> f32x4 {
    f32x4 v = {0.0f, 0.0f, 0.0f, 0.0f};
    if (tt * 32 + ak <= ROWD - 4)
      v = __builtin_nontemporal_load((const f32x4*)(look + arow + tt * 32));
    return v;
  };
  auto writeA = [&](int buf, f32x4 v) {
    uint2 p;
    p.x = (unsigned)f2bf(v[0]) | ((unsigned)f2bf(v[1]) << 16);
    p.y = (unsigned)f2bf(v[2]) | ((unsigned)f2bf(v[3]) << 16);
    *(uint2*)&Ab[buf][ar * 40 + ak] = p;
  };

  f32x4 acc[4][4] = {};
  f32x4 rA0, rA1;

  // prologue: A(0) -> Ab[0]; A(1),A(2) in flight
  writeA(0, loadA(0));
  rA0 = loadA(1);
  rA1 = loadA(2);

#pragma unroll 2
  for (int t = 0; t < NT1; ++t) {
    __syncthreads();   // Ab[t&1] ready
    const int cu = t & 1;

    // B fragments for this tile, straight from L2-resident slab
    const unsigned short* bp = w1 + (size_t)t * (4 * 512 * 8);
    bf16x8 bg[4];
#pragma unroll
    for (int n = 0; n < 4; ++n) bg[n] = *(const bf16x8*)(bp + boff[n]);

    bf16x8 af[4];
#pragma unroll
    for (int m = 0; m < 4; ++m)
      af[m] = *(const bf16x8*)&Ab[cu][(wm * 64 + m * 16 + fr) * 40 + fq * 8];
#pragma unroll
    for (int n = 0; n < 4; ++n)
#pragma unroll
      for (int m = 0; m < 4; ++m)
        acc[m][n] = MFMA16(af[m], bg[n], acc[m][n]);

    // deferred A write (loaded 2 tiles ago), then refill the pipe
    if (cu == 0) { writeA(1, rA0); rA0 = loadA(t + 3); }
    else         { writeA(0, rA1); rA1 = loadA(t + 3); }
  }

  // epilogue: bias + relu + store h in k-chunked slot layout
#pragma unroll
  for (int n = 0; n < 4; ++n) {
    const int col = wn * 64 + n * 16 + fr;
    const int kc = col >> 3, e = col & 7;
    const float bb = b1[col];
    const int chunk = mb * 2 + wm;            // global 64-row chunk
    unsigned short* hb = hout + (((size_t)chunk * 64 + kc) * 64) * 8 + e;
#pragma unroll
    for (int m = 0; m < 4; ++m)
#pragma unroll
      for (int i = 0; i < 4; ++i) {
        const int row = m * 16 + fq * 4 + i;  // within chunk
        const float v = fmaxf(acc[m][n][i] + bb, 0.0f);
        hb[row * 8] = f2bf(v);
      }
  }
}

// ---------- GEMM2 + dot, fully fused, no LDS staging ----------
__global__ __launch_bounds__(512, 2) void ASAECF_gemm2dot(
    const unsigned short* __restrict__ hsl,   // [2][chunk64][kc][row64][8]
    const unsigned short* __restrict__ w2s,   // [2][64][256][8]
    const float* __restrict__ ub2, const float* __restrict__ ib2,
    float* __restrict__ out)
{
  const int tid  = threadIdx.x;
  const int lane = tid & 63, wid = tid >> 6;
  const int fr   = lane & 15, fq = lane >> 4;
  const int rb   = blockIdx.x;          // 32-row block
  const int row0 = rb * 32;

  const unsigned short* __restrict__ hu = hsl;
  const unsigned short* __restrict__ hv = hsl + (size_t)HSL_TW;
  const size_t abase = ((size_t)(rb >> 1) * 64) * 64 * 8;
  const int lrow0 = (rb & 1) * 32;

  f32x4 au[2][2] = {}, av[2][2] = {};

#pragma unroll
  for (int t = 0; t < 8; ++t) {
#pragma unroll
    for (int s = 0; s < 2; ++s) {
      const int kc = t * 8 + s * 4 + fq;
      bf16x8 a_u[2], a_v[2], b_u[2], b_v[2];
#pragma unroll
      for (int m = 0; m < 2; ++m) {
        const size_t off = abase + ((size_t)kc * 64 + lrow0 + m * 16 + fr) * 8;
        a_u[m] = *(const bf16x8*)(hu + off);
        a_v[m] = *(const bf16x8*)(hv + off);
      }
#pragma unroll
      for (int n = 0; n < 2; ++n) {
        const int col = wid * 32 + n * 16 + fr;
        const size_t offb = ((size_t)kc * 256 + col) * 8;
        b_u[n] = *(const bf16x8*)(w2s + offb);
        b_v[n] = *(const bf16x8*)(w2s + (size_t)64 * 256 * 8 + offb);
      }
#pragma unroll
      for (int m = 0; m < 2; ++m)
#pragma unroll
        for (int n = 0; n < 2; ++n) {
          au[m][n] = MFMA16(a_u[m], b_u[n], au[m][n]);
          av[m][n] = MFMA16(a_v[m], b_v[n], av[m][n]);
        }
    }
  }

  // bias + per-row dot + reduction
  __shared__ float red[8][32];
  float bu[2], bv[2];
#pragma unroll
  for (int n = 0; n < 2; ++n) {
    const int col = wid * 32 + n * 16 + fr;
    bu[n] = ub2[col];
    bv[n] = ib2[col];
  }
#pragma unroll
  for (int m = 0; m < 2; ++m)
#pragma unroll
    for (int i = 0; i < 4; ++i) {
      float p = 0.0f;
#pragma unroll
      for (int n = 0; n < 2; ++n)
        p += (au[m][n][i] + bu[n]) * (av[m][n][i] + bv[n]);
      p += __shfl_xor(p, 1, 64);
      p += __shfl_xor(p, 2, 64);
      p += __shfl_xor(p, 4, 64);
      p += __shfl_xor(p, 8, 64);
      if (fr == 0) red[wid][m * 16 + fq * 4 + i] = p;
    }
  __syncthreads();
  if (tid < 32) {
    float s = 0.0f;
#pragma unroll
    for (int w = 0; w < 8; ++w) s += red[w][tid];
    out[row0 + tid] = s;
  }
}

extern "C" void kernel_launch(void* const* d_in, const int* in_sizes, int n_in,
                              void* d_out, int out_size, void* d_ws, size_t ws_size,
                              hipStream_t stream) {
  (void)in_sizes; (void)n_in; (void)out_size; (void)ws_size;
  const int*   x     = (const int*)d_in[0];
  const float* ulook = (const float*)d_in[1];
  const float* ilook = (const float*)d_in[2];
  const float* uW1   = (const float*)d_in[3];
  const float* ub1   = (const float*)d_in[4];
  const float* uW2   = (const float*)d_in[5];
  const float* ub2   = (const float*)d_in[6];
  const float* iW1   = (const float*)d_in[7];
  const float* ib1   = (const float*)d_in[8];
  const float* iW2   = (const float*)d_in[9];
  const float* ib2   = (const float*)d_in[10];
  float* out = (float*)d_out;

  // workspace layout (bytes):
  //   w1s: [2][272][512][8] bf16 = 4,456,448
  //   w2s: [2][64][256][8]  bf16 =   524,288  @ 4,456,448
  //   hsl: [2][8192*512]    bf16 = 16,777,216 @ 4,980,736
  char* ws = (char*)d_ws;
  unsigned short* w1s = (unsigned short*)(ws);
  unsigned short* w2s = (unsigned short*)(ws + 4456448);
  unsigned short* hsl = (unsigned short*)(ws + 4980736);

  ASAECF_tcast<<<dim3(544, 1, 2), 256, 0, stream>>>(uW1, iW1, w1s, 512, 9, ROWD, KC1, 1);
  ASAECF_tcast<<<dim3(64, 1, 2),  256, 0, stream>>>(uW2, iW2, w2s, 256, 8, HID, 64, 0);
  ASAECF_gemm1<<<dim3(128), 1024, 0, stream>>>(x, ulook, ilook, w1s, ub1, ib1, hsl);
  ASAECF_gemm2dot<<<dim3(256), 512, 0, stream>>>(hsl, w2s, ub2, ib2, out);
}

// Round 8
// 80.655 us; speedup vs baseline: 1.5086x; 1.5086x over previous
//
#include <hip/hip_runtime.h>
#include <stdint.h>

typedef __attribute__((ext_vector_type(8))) short bf16x8;
typedef __attribute__((ext_vector_type(4))) float f32x4;

#define MFMA16(a, b, c) __builtin_amdgcn_mfma_f32_16x16x32_bf16((a), (b), (c), 0, 0, 0)

static __device__ __forceinline__ unsigned short f2bf(float f) {
  union { float f; unsigned int u; } cv;
  cv.f = f;
  return (unsigned short)((cv.u + 0x7fffu + ((cv.u >> 16) & 1u)) >> 16);
}

#define BATCH 8192
#define ROWD  2128
#define HID   512
#define LATD  256
#define KC1   272            // 8-elem k-chunks for layer 1 (272*8 = 2176, zero-padded)
#define NT1   68             // 32-k tiles (68*32 = 2176; trailing tiles zero-padded)
#define HSL_TW (BATCH * HID) // ushorts per tower in h_sl

// ---------- prep: k-chunked transpose-cast ----------
__global__ __launch_bounds__(256) void ASAECF_tcast(
    const float* __restrict__ in0, const float* __restrict__ in1,
    unsigned short* __restrict__ out, int N, int lgN, int Kin, int KC, int perm)
{
  const float* __restrict__ in = blockIdx.z ? in1 : in0;
  unsigned short* __restrict__ o = out + (size_t)blockIdx.z * KC * N * 8;
  const int s = blockIdx.x * 256 + threadIdx.x;   // slot index
  const int kc = s >> lgN, n = s & (N - 1);
  unsigned short v[8];
#pragma unroll
  for (int e = 0; e < 8; ++e) {
    const int k = kc * 8 + e;
    float f = 0.0f;
    if (k < Kin) {
      const int src = perm ? (k < 128 ? k + 2000 : k - 128) : k;
      f = in[(size_t)src * N + n];
    }
    v[e] = f2bf(f);
  }
  *(uint4*)(o + (size_t)s * 8) = *(const uint4*)v;
}

// ---------- GEMM1: h = relu(gather(look) @ W1p + b1) ----------
// BM=128, BN=256 (N-half per block), BK=32. 512 threads = 8 waves (2M x 4N),
// wave tile 64x64. Grid = 64 mb x 2 nh x 2 towers = 256 blocks (1/CU).
// B traffic halves vs BM=64 (570 -> 285 MB). The two N-half blocks of an
// M-tile are placed on the SAME XCD in ADJACENT dispatch slots so their
// duplicate row-gathers hit L2/L3 (HBM gather stays ~139 MB).
__global__ __launch_bounds__(512) void ASAECF_gemm1(
    const int* __restrict__ x,
    const float* __restrict__ ulook, const float* __restrict__ ilook,
    const unsigned short* __restrict__ w1s,   // [2][KC1][512][8]
    const float* __restrict__ ub1, const float* __restrict__ ib1,
    unsigned short* __restrict__ hsl)         // [2][chunk64][kc][row64][8]
{
  // bid -> (xcd, idx): tower = xcd>>2, nh = idx&1 (pair adjacent), mb = (xcd&3)*16 + idx>>1
  const int bid   = blockIdx.x;             // 0..255
  const int xcd   = bid & 7;
  const int idx   = bid >> 3;               // 0..31
  const int tower = xcd >> 2;
  const int nh    = idx & 1;
  const int mb    = (xcd & 3) * 16 + (idx >> 1);   // 0..63

  const float* __restrict__ look = tower ? ilook : ulook;
  const unsigned short* __restrict__ w1 = w1s + (size_t)tower * KC1 * HID * 8;
  const float* __restrict__ b1 = tower ? ib1 : ub1;
  unsigned short* __restrict__ hout = hsl + (size_t)tower * HSL_TW;

  __shared__ unsigned short Ab[2][128 * 40];  // 128 rows x 32 k, 80-B padded rows

  const int tid  = threadIdx.x;
  const int lane = tid & 63, wid = tid >> 6;
  const int wm   = wid >> 2, wn = wid & 3;    // wave tile: rows wm*64, cols wn*64
  const int fr   = lane & 15, fq = lane >> 4;
  const int row0 = mb * 128;

  // A staging: thread -> (row ar, 8 consecutive k at ak8)
  const int ar  = tid >> 2;                  // 0..127
  const int ak8 = (tid & 3) * 8;             // 0,8,16,24
  const long long arow = (long long)x[(row0 + ar) * 2 + tower] * ROWD + ak8;

  // B fragment offsets within one k-tile slab (4*512*8 ushorts)
  int boff[4];
#pragma unroll
  for (int n = 0; n < 4; ++n)
    boff[n] = (fq * 512 + nh * 256 + wn * 64 + n * 16 + fr) * 8;

  struct A8 { f32x4 a, b; };
  auto loadA = [&](int tt) -> A8 {
    A8 v;
    v.a = f32x4{0.0f, 0.0f, 0.0f, 0.0f};
    v.b = f32x4{0.0f, 0.0f, 0.0f, 0.0f};
    if (tt * 32 + ak8 + 8 <= ROWD) {
      v.a = *(const f32x4*)(look + arow + tt * 32);
      v.b = *(const f32x4*)(look + arow + tt * 32 + 4);
    }
    return v;
  };
  auto writeA = [&](int buf, A8 v) {
    uint2 p, q;
    p.x = (unsigned)f2bf(v.a[0]) | ((unsigned)f2bf(v.a[1]) << 16);
    p.y = (unsigned)f2bf(v.a[2]) | ((unsigned)f2bf(v.a[3]) << 16);
    q.x = (unsigned)f2bf(v.b[0]) | ((unsigned)f2bf(v.b[1]) << 16);
    q.y = (unsigned)f2bf(v.b[2]) | ((unsigned)f2bf(v.b[3]) << 16);
    *(uint2*)&Ab[buf][ar * 40 + ak8] = p;
    *(uint2*)&Ab[buf][ar * 40 + ak8 + 4] = q;
  };

  f32x4 acc[4][4] = {};
  bf16x8 bgc[4], bgn[4];
  A8 rA0, rA1;

  // prologue: A(0) -> Ab[0]; A(1),A(2) in flight; B(0) in flight
  writeA(0, loadA(0));
  rA0 = loadA(1);
  rA1 = loadA(2);
#pragma unroll
  for (int n = 0; n < 4; ++n) bgc[n] = *(const bf16x8*)(w1 + boff[n]);

#pragma unroll 2
  for (int t = 0; t < NT1; ++t) {
    __syncthreads();   // Ab[t&1] ready
    const int cu = t & 1;

    // B prefetch for t+1 (stays in flight through this tile's MFMAs)
    const unsigned short* bpn = w1 + (size_t)(t + 1) * (4 * 512 * 8);
#pragma unroll
    for (int n = 0; n < 4; ++n) bgn[n] = *(const bf16x8*)(bpn + boff[n]);

    bf16x8 af[4];
#pragma unroll
    for (int m = 0; m < 4; ++m)
      af[m] = *(const bf16x8*)&Ab[cu][(wm * 64 + m * 16 + fr) * 40 + fq * 8];
#pragma unroll
    for (int n = 0; n < 4; ++n)
#pragma unroll
      for (int m = 0; m < 4; ++m)
        acc[m][n] = MFMA16(af[m], bgc[n], acc[m][n]);

    // deferred A write (loaded 2 tiles ago), then refill the pipe
    if (cu == 0) { writeA(1, rA0); rA0 = loadA(t + 3); }
    else         { writeA(0, rA1); rA1 = loadA(t + 3); }

#pragma unroll
    for (int n = 0; n < 4; ++n) bgc[n] = bgn[n];
  }

  // epilogue: bias + relu + store h in k-chunked slot layout
#pragma unroll
  for (int n = 0; n < 4; ++n) {
    const int col = nh * 256 + wn * 64 + n * 16 + fr;
    const int kc = col >> 3, e = col & 7;
    const float bb = b1[col];
    const int chunk = mb * 2 + wm;            // global 64-row chunk
    unsigned short* hb = hout + (((size_t)chunk * 64 + kc) * 64) * 8 + e;
#pragma unroll
    for (int m = 0; m < 4; ++m)
#pragma unroll
      for (int i = 0; i < 4; ++i) {
        const int row = m * 16 + fq * 4 + i;  // within chunk
        const float v = fmaxf(acc[m][n][i] + bb, 0.0f);
        hb[row * 8] = f2bf(v);
      }
  }
}

// ---------- GEMM2 + dot, fully fused, no LDS staging ----------
__global__ __launch_bounds__(512, 2) void ASAECF_gemm2dot(
    const unsigned short* __restrict__ hsl,   // [2][chunk64][kc][row64][8]
    const unsigned short* __restrict__ w2s,   // [2][64][256][8]
    const float* __restrict__ ub2, const float* __restrict__ ib2,
    float* __restrict__ out)
{
  const int tid  = threadIdx.x;
  const int lane = tid & 63, wid = tid >> 6;
  const int fr   = lane & 15, fq = lane >> 4;
  const int rb   = blockIdx.x;          // 32-row block
  const int row0 = rb * 32;

  const unsigned short* __restrict__ hu = hsl;
  const unsigned short* __restrict__ hv = hsl + (size_t)HSL_TW;
  const size_t abase = ((size_t)(rb >> 1) * 64) * 64 * 8;
  const int lrow0 = (rb & 1) * 32;

  f32x4 au[2][2] = {}, av[2][2] = {};

#pragma unroll
  for (int t = 0; t < 8; ++t) {
#pragma unroll
    for (int s = 0; s < 2; ++s) {
      const int kc = t * 8 + s * 4 + fq;
      bf16x8 a_u[2], a_v[2], b_u[2], b_v[2];
#pragma unroll
      for (int m = 0; m < 2; ++m) {
        const size_t off = abase + ((size_t)kc * 64 + lrow0 + m * 16 + fr) * 8;
        a_u[m] = *(const bf16x8*)(hu + off);
        a_v[m] = *(const bf16x8*)(hv + off);
      }
#pragma unroll
      for (int n = 0; n < 2; ++n) {
        const int col = wid * 32 + n * 16 + fr;
        const size_t offb = ((size_t)kc * 256 + col) * 8;
        b_u[n] = *(const bf16x8*)(w2s + offb);
        b_v[n] = *(const bf16x8*)(w2s + (size_t)64 * 256 * 8 + offb);
      }
#pragma unroll
      for (int m = 0; m < 2; ++m)
#pragma unroll
        for (int n = 0; n < 2; ++n) {
          au[m][n] = MFMA16(a_u[m], b_u[n], au[m][n]);
          av[m][n] = MFMA16(a_v[m], b_v[n], av[m][n]);
        }
    }
  }

  // bias + per-row dot + reduction
  __shared__ float red[8][32];
  float bu[2], bv[2];
#pragma unroll
  for (int n = 0; n < 2; ++n) {
    const int col = wid * 32 + n * 16 + fr;
    bu[n] = ub2[col];
    bv[n] = ib2[col];
  }
#pragma unroll
  for (int m = 0; m < 2; ++m)
#pragma unroll
    for (int i = 0; i < 4; ++i) {
      float p = 0.0f;
#pragma unroll
      for (int n = 0; n < 2; ++n)
        p += (au[m][n][i] + bu[n]) * (av[m][n][i] + bv[n]);
      p += __shfl_xor(p, 1, 64);
      p += __shfl_xor(p, 2, 64);
      p += __shfl_xor(p, 4, 64);
      p += __shfl_xor(p, 8, 64);
      if (fr == 0) red[wid][m * 16 + fq * 4 + i] = p;
    }
  __syncthreads();
  if (tid < 32) {
    float s = 0.0f;
#pragma unroll
    for (int w = 0; w < 8; ++w) s += red[w][tid];
    out[row0 + tid] = s;
  }
}

extern "C" void kernel_launch(void* const* d_in, const int* in_sizes, int n_in,
                              void* d_out, int out_size, void* d_ws, size_t ws_size,
                              hipStream_t stream) {
  (void)in_sizes; (void)n_in; (void)out_size; (void)ws_size;
  const int*   x     = (const int*)d_in[0];
  const float* ulook = (const float*)d_in[1];
  const float* ilook = (const float*)d_in[2];
  const float* uW1   = (const float*)d_in[3];
  const float* ub1   = (const float*)d_in[4];
  const float* uW2   = (const float*)d_in[5];
  const float* ub2   = (const float*)d_in[6];
  const float* iW1   = (const float*)d_in[7];
  const float* ib1   = (const float*)d_in[8];
  const float* iW2   = (const float*)d_in[9];
  const float* ib2   = (const float*)d_in[10];
  float* out = (float*)d_out;

  // workspace layout (bytes):
  //   w1s: [2][272][512][8] bf16 = 4,456,448
  //   w2s: [2][64][256][8]  bf16 =   524,288  @ 4,456,448
  //   hsl: [2][8192*512]    bf16 = 16,777,216 @ 4,980,736
  char* ws = (char*)d_ws;
  unsigned short* w1s = (unsigned short*)(ws);
  unsigned short* w2s = (unsigned short*)(ws + 4456448);
  unsigned short* hsl = (unsigned short*)(ws + 4980736);

  ASAECF_tcast<<<dim3(544, 1, 2), 256, 0, stream>>>(uW1, iW1, w1s, 512, 9, ROWD, KC1, 1);
  ASAECF_tcast<<<dim3(64, 1, 2),  256, 0, stream>>>(uW2, iW2, w2s, 256, 8, HID, 64, 0);
  ASAECF_gemm1<<<dim3(256), 512, 0, stream>>>(x, ulook, ilook, w1s, ub1, ib1, hsl);
  ASAECF_gemm2dot<<<dim3(256), 512, 0, stream>>>(hsl, w2s, ub2, ib2, out);
}

// Round 9
// 80.473 us; speedup vs baseline: 1.5120x; 1.0023x over previous
//
#include <hip/hip_runtime.h>
#include <stdint.h>

typedef __attribute__((ext_vector_type(8))) short bf16x8;
typedef __attribute__((ext_vector_type(4))) float f32x4;

#define MFMA16(a, b, c) __builtin_amdgcn_mfma_f32_16x16x32_bf16((a), (b), (c), 0, 0, 0)

static __device__ __forceinline__ unsigned short f2bf(float f) {
  union { float f; unsigned int u; } cv;
  cv.f = f;
  return (unsigned short)((cv.u + 0x7fffu + ((cv.u >> 16) & 1u)) >> 16);
}

#define BATCH 8192
#define ROWD  2128
#define HID   512
#define LATD  256
#define KC1   272            // 8-elem k-chunks for layer 1 (272*8 = 2176, zero-padded)
#define NT1   68             // 32-k tiles (68*32 = 2176; trailing tiles zero-padded)
#define HSL_TW (BATCH * HID) // ushorts per tower in h_sl

// ---------- prep: k-chunked transpose-cast ----------
__global__ __launch_bounds__(256) void ASAECF_tcast(
    const float* __restrict__ in0, const float* __restrict__ in1,
    unsigned short* __restrict__ out, int N, int lgN, int Kin, int KC, int perm)
{
  const float* __restrict__ in = blockIdx.z ? in1 : in0;
  unsigned short* __restrict__ o = out + (size_t)blockIdx.z * KC * N * 8;
  const int s = blockIdx.x * 256 + threadIdx.x;   // slot index
  const int kc = s >> lgN, n = s & (N - 1);
  unsigned short v[8];
#pragma unroll
  for (int e = 0; e < 8; ++e) {
    const int k = kc * 8 + e;
    float f = 0.0f;
    if (k < Kin) {
      const int src = perm ? (k < 128 ? k + 2000 : k - 128) : k;
      f = in[(size_t)src * N + n];
    }
    v[e] = f2bf(f);
  }
  *(uint4*)(o + (size_t)s * 8) = *(const uint4*)v;
}

// ---------- GEMM1: h = relu(gather(look) @ W1p + b1) ----------
// BM=128, BN=256, BK=32. 512 threads = 8 waves (2M x 4N), wave tile 64x64.
// Grid = 64 mb x 2 nh x 2 towers = 256 blocks (1/CU).
// SINGLE CHANGE vs R8: the per-tile __syncthreads() is replaced by
// { s_waitcnt lgkmcnt(0); s_barrier } so in-flight global loads (A gather
// pipelined 2 tiles ahead, B prefetch 1 tile ahead) are NOT drained at the
// barrier -- the compiler emits counted vmcnt for their uses instead.
__global__ __launch_bounds__(512) void ASAECF_gemm1(
    const int* __restrict__ x,
    const float* __restrict__ ulook, const float* __restrict__ ilook,
    const unsigned short* __restrict__ w1s,   // [2][KC1][512][8]
    const float* __restrict__ ub1, const float* __restrict__ ib1,
    unsigned short* __restrict__ hsl)         // [2][chunk64][kc][row64][8]
{
  // bid -> (xcd, idx): tower = xcd>>2, nh = idx&1 (pair adjacent), mb = (xcd&3)*16 + idx>>1
  const int bid   = blockIdx.x;             // 0..255
  const int xcd   = bid & 7;
  const int idx   = bid >> 3;               // 0..31
  const int tower = xcd >> 2;
  const int nh    = idx & 1;
  const int mb    = (xcd & 3) * 16 + (idx >> 1);   // 0..63

  const float* __restrict__ look = tower ? ilook : ulook;
  const unsigned short* __restrict__ w1 = w1s + (size_t)tower * KC1 * HID * 8;
  const float* __restrict__ b1 = tower ? ib1 : ub1;
  unsigned short* __restrict__ hout = hsl + (size_t)tower * HSL_TW;

  __shared__ unsigned short Ab[2][128 * 40];  // 128 rows x 32 k, 80-B padded rows

  const int tid  = threadIdx.x;
  const int lane = tid & 63, wid = tid >> 6;
  const int wm   = wid >> 2, wn = wid & 3;    // wave tile: rows wm*64, cols wn*64
  const int fr   = lane & 15, fq = lane >> 4;
  const int row0 = mb * 128;

  // A staging: thread -> (row ar, 8 consecutive k at ak8)
  const int ar  = tid >> 2;                  // 0..127
  const int ak8 = (tid & 3) * 8;             // 0,8,16,24
  const long long arow = (long long)x[(row0 + ar) * 2 + tower] * ROWD + ak8;

  // B fragment offsets within one k-tile slab (4*512*8 ushorts)
  int boff[4];
#pragma unroll
  for (int n = 0; n < 4; ++n)
    boff[n] = (fq * 512 + nh * 256 + wn * 64 + n * 16 + fr) * 8;

  struct A8 { f32x4 a, b; };
  auto loadA = [&](int tt) -> A8 {
    A8 v;
    v.a = f32x4{0.0f, 0.0f, 0.0f, 0.0f};
    v.b = f32x4{0.0f, 0.0f, 0.0f, 0.0f};
    if (tt * 32 + ak8 + 8 <= ROWD) {
      v.a = *(const f32x4*)(look + arow + tt * 32);
      v.b = *(const f32x4*)(look + arow + tt * 32 + 4);
    }
    return v;
  };
  auto writeA = [&](int buf, A8 v) {
    uint2 p, q;
    p.x = (unsigned)f2bf(v.a[0]) | ((unsigned)f2bf(v.a[1]) << 16);
    p.y = (unsigned)f2bf(v.a[2]) | ((unsigned)f2bf(v.a[3]) << 16);
    q.x = (unsigned)f2bf(v.b[0]) | ((unsigned)f2bf(v.b[1]) << 16);
    q.y = (unsigned)f2bf(v.b[2]) | ((unsigned)f2bf(v.b[3]) << 16);
    *(uint2*)&Ab[buf][ar * 40 + ak8] = p;
    *(uint2*)&Ab[buf][ar * 40 + ak8 + 4] = q;
  };

  f32x4 acc[4][4] = {};
  bf16x8 bgc[4], bgn[4];
  A8 rA0, rA1;

  // prologue: A(0) -> Ab[0]; A(1),A(2) in flight; B(0) in flight
  writeA(0, loadA(0));
  rA0 = loadA(1);
  rA1 = loadA(2);
#pragma unroll
  for (int n = 0; n < 4; ++n) bgc[n] = *(const bf16x8*)(w1 + boff[n]);

  // seam: drain LDS ops only; leave global loads in flight
  asm volatile("s_waitcnt lgkmcnt(0)" ::: "memory");
  __builtin_amdgcn_s_barrier();

#pragma unroll 2
  for (int t = 0; t < NT1; ++t) {
    const int cu = t & 1;

    // B prefetch for t+1 (stays in flight through this tile's MFMAs)
    const unsigned short* bpn = w1 + (size_t)(t + 1) * (4 * 512 * 8);
#pragma unroll
    for (int n = 0; n < 4; ++n) bgn[n] = *(const bf16x8*)(bpn + boff[n]);

    bf16x8 af[4];
#pragma unroll
    for (int m = 0; m < 4; ++m)
      af[m] = *(const bf16x8*)&Ab[cu][(wm * 64 + m * 16 + fr) * 40 + fq * 8];
#pragma unroll
    for (int n = 0; n < 4; ++n)
#pragma unroll
      for (int m = 0; m < 4; ++m)
        acc[m][n] = MFMA16(af[m], bgc[n], acc[m][n]);

    // deferred A write (loaded 2 tiles ago), then refill the pipe
    if (cu == 0) { writeA(1, rA0); rA0 = loadA(t + 3); }
    else         { writeA(0, rA1); rA1 = loadA(t + 3); }

#pragma unroll
    for (int n = 0; n < 4; ++n) bgc[n] = bgn[n];

    // seam: LDS visibility only, no vmem drain
    asm volatile("s_waitcnt lgkmcnt(0)" ::: "memory");
    __builtin_amdgcn_s_barrier();
  }

  // epilogue: bias + relu + store h in k-chunked slot layout
#pragma unroll
  for (int n = 0; n < 4; ++n) {
    const int col = nh * 256 + wn * 64 + n * 16 + fr;
    const int kc = col >> 3, e = col & 7;
    const float bb = b1[col];
    const int chunk = mb * 2 + wm;            // global 64-row chunk
    unsigned short* hb = hout + (((size_t)chunk * 64 + kc) * 64) * 8 + e;
#pragma unroll
    for (int m = 0; m < 4; ++m)
#pragma unroll
      for (int i = 0; i < 4; ++i) {
        const int row = m * 16 + fq * 4 + i;  // within chunk
        const float v = fmaxf(acc[m][n][i] + bb, 0.0f);
        hb[row * 8] = f2bf(v);
      }
  }
}

// ---------- GEMM2 + dot, fully fused, no LDS staging ----------
__global__ __launch_bounds__(512, 2) void ASAECF_gemm2dot(
    const unsigned short* __restrict__ hsl,   // [2][chunk64][kc][row64][8]
    const unsigned short* __restrict__ w2s,   // [2][64][256][8]
    const float* __restrict__ ub2, const float* __restrict__ ib2,
    float* __restrict__ out)
{
  const int tid  = threadIdx.x;
  const int lane = tid & 63, wid = tid >> 6;
  const int fr   = lane & 15, fq = lane >> 4;
  const int rb   = blockIdx.x;          // 32-row block
  const int row0 = rb * 32;

  const unsigned short* __restrict__ hu = hsl;
  const unsigned short* __restrict__ hv = hsl + (size_t)HSL_TW;
  const size_t abase = ((size_t)(rb >> 1) * 64) * 64 * 8;
  const int lrow0 = (rb & 1) * 32;

  f32x4 au[2][2] = {}, av[2][2] = {};

#pragma unroll
  for (int t = 0; t < 8; ++t) {
#pragma unroll
    for (int s = 0; s < 2; ++s) {
      const int kc = t * 8 + s * 4 + fq;
      bf16x8 a_u[2], a_v[2], b_u[2], b_v[2];
#pragma unroll
      for (int m = 0; m < 2; ++m) {
        const size_t off = abase + ((size_t)kc * 64 + lrow0 + m * 16 + fr) * 8;
        a_u[m] = *(const bf16x8*)(hu + off);
        a_v[m] = *(const bf16x8*)(hv + off);
      }
#pragma unroll
      for (int n = 0; n < 2; ++n) {
        const int col = wid * 32 + n * 16 + fr;
        const size_t offb = ((size_t)kc * 256 + col) * 8;
        b_u[n] = *(const bf16x8*)(w2s + offb);
        b_v[n] = *(const bf16x8*)(w2s + (size_t)64 * 256 * 8 + offb);
      }
#pragma unroll
      for (int m = 0; m < 2; ++m)
#pragma unroll
        for (int n = 0; n < 2; ++n) {
          au[m][n] = MFMA16(a_u[m], b_u[n], au[m][n]);
          av[m][n] = MFMA16(a_v[m], b_v[n], av[m][n]);
        }
    }
  }

  // bias + per-row dot + reduction
  __shared__ float red[8][32];
  float bu[2], bv[2];
#pragma unroll
  for (int n = 0; n < 2; ++n) {
    const int col = wid * 32 + n * 16 + fr;
    bu[n] = ub2[col];
    bv[n] = ib2[col];
  }
#pragma unroll
  for (int m = 0; m < 2; ++m)
#pragma unroll
    for (int i = 0; i < 4; ++i) {
      float p = 0.0f;
#pragma unroll
      for (int n = 0; n < 2; ++n)
        p += (au[m][n][i] + bu[n]) * (av[m][n][i] + bv[n]);
      p += __shfl_xor(p, 1, 64);
      p += __shfl_xor(p, 2, 64);
      p += __shfl_xor(p, 4, 64);
      p += __shfl_xor(p, 8, 64);
      if (fr == 0) red[wid][m * 16 + fq * 4 + i] = p;
    }
  __syncthreads();
  if (tid < 32) {
    float s = 0.0f;
#pragma unroll
    for (int w = 0; w < 8; ++w) s += red[w][tid];
    out[row0 + tid] = s;
  }
}

extern "C" void kernel_launch(void* const* d_in, const int* in_sizes, int n_in,
                              void* d_out, int out_size, void* d_ws, size_t ws_size,
                              hipStream_t stream) {
  (void)in_sizes; (void)n_in; (void)out_size; (void)ws_size;
  const int*   x     = (const int*)d_in[0];
  const float* ulook = (const float*)d_in[1];
  const float* ilook = (const float*)d_in[2];
  const float* uW1   = (const float*)d_in[3];
  const float* ub1   = (const float*)d_in[4];
  const float* uW2   = (const float*)d_in[5];
  const float* ub2   = (const float*)d_in[6];
  const float* iW1   = (const float*)d_in[7];
  const float* ib1   = (const float*)d_in[8];
  const float* iW2   = (const float*)d_in[9];
  const float* ib2   = (const float*)d_in[10];
  float* out = (float*)d_out;

  // workspace layout (bytes):
  //   w1s: [2][272][512][8] bf16 = 4,456,448
  //   w2s: [2][64][256][8]  bf16 =   524,288  @ 4,456,448
  //   hsl: [2][8192*512]    bf16 = 16,777,216 @ 4,980,736
  char* ws = (char*)d_ws;
  unsigned short* w1s = (unsigned short*)(ws);
  unsigned short* w2s = (unsigned short*)(ws + 4456448);
  unsigned short* hsl = (unsigned short*)(ws + 4980736);

  ASAECF_tcast<<<dim3(544, 1, 2), 256, 0, stream>>>(uW1, iW1, w1s, 512, 9, ROWD, KC1, 1);
  ASAECF_tcast<<<dim3(64, 1, 2),  256, 0, stream>>>(uW2, iW2, w2s, 256, 8, HID, 64, 0);
  ASAECF_gemm1<<<dim3(256), 512, 0, stream>>>(x, ulook, ilook, w1s, ub1, ib1, hsl);
  ASAECF_gemm2dot<<<dim3(256), 512, 0, stream>>>(hsl, w2s, ub2, ib2, out);
}